// Round 1
// baseline (17325.420 us; speedup 1.0000x reference)
//
#include <hip/hip_runtime.h>
#include <math.h>

// ---------------------------------------------------------------------------
// Decision-transformer forward on MI355X.
// B=8,T=64,N=16,DS=128,A=32,C=1024,H=16,L=8 -> BN=128, S=128, d=64, M=BN*S=16384
// Residual stream x: fp32. GEMM inputs: bf16 (fp32 accum via MFMA).
// ---------------------------------------------------------------------------

typedef float  float4v __attribute__((ext_vector_type(4)));
typedef short  short8  __attribute__((ext_vector_type(8)));

__device__ inline unsigned short f2b(float f) {           // fp32 -> bf16 (RNE)
    unsigned int u = __float_as_uint(f);
    u += 0x7fffu + ((u >> 16) & 1u);
    return (unsigned short)(u >> 16);
}
__device__ inline float gelu_f(float v) {                 // tanh-approx GELU
    return 0.5f * v * (1.0f + tanhf(0.7978845608028654f * (v + 0.044715f * v * v * v)));
}
__device__ inline float4v mfma16(short8 a, short8 b, float4v c) {
    return __builtin_amdgcn_mfma_f32_16x16x32_bf16(a, b, c, 0, 0, 0);
}
#define GLOAD_LDS16(gp, lp)                                                 \
    __builtin_amdgcn_global_load_lds(                                       \
        (__attribute__((address_space(1))) void*)(gp),                      \
        (__attribute__((address_space(3))) void*)(lp), 16, 0, 0)

// ---------------------------------------------------------------------------
// Embedding: x[bn*128+s][c] = token_embed + pos_emb[s] + global_pos_emb[ts]
// grid (8 col-tiles of 128, 512 row-tiles of 32), block 256
// ---------------------------------------------------------------------------
__global__ __launch_bounds__(256) void embed_kernel(
    const float* __restrict__ states, const float* __restrict__ actions,
    const int* __restrict__ timesteps, const float* __restrict__ pos_emb,
    const float* __restrict__ gpe_tab, const float* __restrict__ seW,
    const float* __restrict__ seb, const float* __restrict__ aeW,
    const float* __restrict__ aeb, float* __restrict__ x)
{
    const int c0 = blockIdx.x * 128;
    const int m0 = blockIdx.y * 32;
    const int bn = m0 >> 7;
    const int b  = bn >> 4, n = bn & 15;
    const int s_base = m0 & 127;            // multiple of 32
    const int tid = threadIdx.x;

    __shared__ float st[16][128];           // 16 even-s rows (states)
    __shared__ float ac[16][32];            // 16 odd-s rows (actions)
    for (int idx = tid; idx < 16 * 128; idx += 256) {
        int rr = idx >> 7, ds = idx & 127;
        int t = (s_base >> 1) + rr;
        st[rr][ds] = states[(((size_t)b * 64 + t) * 16 + n) * 128 + ds];
    }
    for (int idx = tid; idx < 16 * 32; idx += 256) {
        int rr = idx >> 5, a = idx & 31;
        int t = (s_base >> 1) + rr;
        ac[rr][a] = actions[(((size_t)b * 64 + t) * 16 + n) * 32 + a];
    }
    __syncthreads();

    const int half = tid >> 7;              // 0: even s (state), 1: odd s (action)
    const int sub  = tid & 127;
    const int cg   = sub & 31;              // 4-col group within 128-col tile
    const int rg   = sub >> 5;              // 4-row group within 16 rows

    float acc[4][4];
    for (int i = 0; i < 4; i++) for (int j = 0; j < 4; j++) acc[i][j] = 0.f;

    if (half == 0) {
        for (int kk = 0; kk < 128; kk++) {
            float4 w4 = *(const float4*)&seW[(size_t)kk * 1024 + c0 + cg * 4];
            for (int r4 = 0; r4 < 4; r4++) {
                float sv = st[rg * 4 + r4][kk];
                acc[r4][0] += sv * w4.x; acc[r4][1] += sv * w4.y;
                acc[r4][2] += sv * w4.z; acc[r4][3] += sv * w4.w;
            }
        }
    } else {
        for (int kk = 0; kk < 32; kk++) {
            float4 w4 = *(const float4*)&aeW[(size_t)kk * 1024 + c0 + cg * 4];
            for (int r4 = 0; r4 < 4; r4++) {
                float sv = ac[rg * 4 + r4][kk];
                acc[r4][0] += sv * w4.x; acc[r4][1] += sv * w4.y;
                acc[r4][2] += sv * w4.z; acc[r4][3] += sv * w4.w;
            }
        }
    }
    const float* bias = half ? aeb : seb;
    float4 b4 = *(const float4*)&bias[c0 + cg * 4];
    for (int r4 = 0; r4 < 4; r4++) {
        int rr = rg * 4 + r4;
        int s  = s_base + rr * 2 + half;
        int t  = (s_base >> 1) + rr;
        int m  = bn * 128 + s;
        int ts = timesteps[b * 64 + t];
        float4 p4 = *(const float4*)&pos_emb[(size_t)s * 1024 + c0 + cg * 4];
        float4 g4 = *(const float4*)&gpe_tab[(size_t)ts * 1024 + c0 + cg * 4];
        float4 o;
        o.x = acc[r4][0] + b4.x + p4.x + g4.x;
        o.y = acc[r4][1] + b4.y + p4.y + g4.y;
        o.z = acc[r4][2] + b4.z + p4.z + g4.z;
        o.w = acc[r4][3] + b4.w + p4.w + g4.w;
        *(float4*)&x[(size_t)m * 1024 + c0 + cg * 4] = o;
    }
}

// ---------------------------------------------------------------------------
// Weight transpose + fp32->bf16:  src[K,N] f32  ->  dst[N,K] bf16
// grid (N/32, K/32), block 256
// ---------------------------------------------------------------------------
__global__ __launch_bounds__(256) void transpose_kernel(
    const float* __restrict__ src, unsigned short* __restrict__ dst, int K, int N)
{
    __shared__ float tile[32][33];
    const int n0 = blockIdx.x * 32, k0 = blockIdx.y * 32;
    const int tid = threadIdx.x;
    const int r = tid >> 5, c = tid & 31;
    for (int i = 0; i < 4; i++)
        tile[r + i * 8][c] = src[(size_t)(k0 + r + i * 8) * N + n0 + c];
    __syncthreads();
    for (int i = 0; i < 4; i++)
        dst[(size_t)(n0 + r + i * 8) * K + k0 + c] = f2b(tile[c][r + i * 8]);
}

// ---------------------------------------------------------------------------
// LayerNorm: x fp32 [rows,1024] -> out bf16, one block per row
// ---------------------------------------------------------------------------
__global__ __launch_bounds__(256) void ln_kernel(
    const float* __restrict__ x, const float* __restrict__ w,
    const float* __restrict__ b, unsigned short* __restrict__ out)
{
    const int row = blockIdx.x;
    const int tid = threadIdx.x;
    const float* xr = x + (size_t)row * 1024;
    float4 v = *(const float4*)&xr[tid * 4];
    float s  = v.x + v.y + v.z + v.w;
    float s2 = v.x * v.x + v.y * v.y + v.z * v.z + v.w * v.w;
    for (int o = 32; o > 0; o >>= 1) { s += __shfl_down(s, o); s2 += __shfl_down(s2, o); }
    __shared__ float ls[4], ls2[4];
    if ((tid & 63) == 0) { ls[tid >> 6] = s; ls2[tid >> 6] = s2; }
    __syncthreads();
    s  = ls[0] + ls[1] + ls[2] + ls[3];
    s2 = ls2[0] + ls2[1] + ls2[2] + ls2[3];
    float mean = s * (1.f / 1024.f);
    float var  = s2 * (1.f / 1024.f) - mean * mean;
    float inv  = rsqrtf(var + 1e-5f);
    float4 wv = *(const float4*)&w[tid * 4];
    float4 bv = *(const float4*)&b[tid * 4];
    unsigned short o4[4];
    o4[0] = f2b((v.x - mean) * inv * wv.x + bv.x);
    o4[1] = f2b((v.y - mean) * inv * wv.y + bv.y);
    o4[2] = f2b((v.z - mean) * inv * wv.z + bv.z);
    o4[3] = f2b((v.w - mean) * inv * wv.w + bv.w);
    *(uint2*)&out[(size_t)row * 1024 + tid * 4] = *(uint2*)o4;
}

// ---------------------------------------------------------------------------
// GEMM: out[M,N] = A[M,K](bf16) @ Bt[N,K](bf16)^T + bias (+resid)
// m97 structure: 128x128 tile, BK=32, 4 waves each 64x64 (4x4 of 16x16x32 MFMA),
// global_load_lds width-16 staging, [row][k] LDS layout (no pad: 2-way is free).
// MODE 0: out bf16 = acc+bias   1: out bf16 = gelu(acc+bias)
// MODE 2: out fp32 = acc+bias+resid
// ---------------------------------------------------------------------------
template <int MODE>
__global__ __launch_bounds__(256) void gemm_kernel(
    const unsigned short* __restrict__ A, const unsigned short* __restrict__ Bt,
    const float* __restrict__ bias, const float* __restrict__ resid,
    void* __restrict__ outp, int M, int N, int K)
{
    __shared__ unsigned short As[128][32];
    __shared__ unsigned short Bs[128][32];
    const int tid = threadIdx.x;
    const int w  = tid >> 6, l = tid & 63;
    const int wr = w >> 1, wc = w & 1;
    const int qd = l >> 4, r = l & 15;
    const int m0 = blockIdx.y * 128, n0 = blockIdx.x * 128;

    const unsigned short* Ab = A  + (size_t)m0 * K;
    const unsigned short* Bb = Bt + (size_t)n0 * K;

    float4v acc[4][4];
    float4v zero = {0.f, 0.f, 0.f, 0.f};
    for (int i = 0; i < 4; i++) for (int j = 0; j < 4; j++) acc[i][j] = zero;

    // staging: 512 16B-segments per tile, 2 per thread per tile
    const int ra0 = tid >> 2,        ca0 = (tid & 3) * 8;
    const int ra1 = (tid + 256) >> 2, ca1 = ((tid + 256) & 3) * 8;

    for (int k0 = 0; k0 < K; k0 += 32) {
        GLOAD_LDS16(Ab + (size_t)ra0 * K + k0 + ca0, &As[ra0][ca0]);
        GLOAD_LDS16(Ab + (size_t)ra1 * K + k0 + ca1, &As[ra1][ca1]);
        GLOAD_LDS16(Bb + (size_t)ra0 * K + k0 + ca0, &Bs[ra0][ca0]);
        GLOAD_LDS16(Bb + (size_t)ra1 * K + k0 + ca1, &Bs[ra1][ca1]);
        __syncthreads();   // drains vmcnt -> LDS valid
        short8 af[4], bfv[4];
        for (int i = 0; i < 4; i++) af[i]  = *(const short8*)&As[wr * 64 + i * 16 + r][qd * 8];
        for (int j = 0; j < 4; j++) bfv[j] = *(const short8*)&Bs[wc * 64 + j * 16 + r][qd * 8];
        for (int i = 0; i < 4; i++)
            for (int j = 0; j < 4; j++)
                acc[i][j] = mfma16(af[i], bfv[j], acc[i][j]);
        __syncthreads();
    }

    // epilogue: C/D layout col = lane&15, row = (lane>>4)*4 + reg  [m89/m91]
    for (int i = 0; i < 4; i++) {
        const int rowb = m0 + wr * 64 + i * 16 + qd * 4;
        for (int j = 0; j < 4; j++) {
            const int col = n0 + wc * 64 + j * 16 + r;
            const float bv = bias[col];
            for (int t4 = 0; t4 < 4; t4++) {
                const int row = rowb + t4;
                float v = acc[i][j][t4] + bv;
                if (MODE == 1) v = gelu_f(v);
                if (MODE == 2) {
                    ((float*)outp)[(size_t)row * N + col] =
                        v + resid[(size_t)row * N + col];
                } else {
                    ((unsigned short*)outp)[(size_t)row * N + col] = f2b(v);
                }
            }
        }
    }
}

// ---------------------------------------------------------------------------
// Attention: one block per (bn, head). S=128, d=64. Causal softmax.
// QK^T and PV via MFMA; softmax fp32 in LDS; P (bf16, unnormalized exp)
// reuses the dead Q/K buffer; output scaled by 1/l in epilogue.
// LDS: 32K (QK/P) + 16K (Vt) + 64K (Sc) + 0.5K = 112.5KB
// ---------------------------------------------------------------------------
__global__ __launch_bounds__(256) void attn_kernel(
    const unsigned short* __restrict__ qm, const unsigned short* __restrict__ km,
    const unsigned short* __restrict__ vm, unsigned short* __restrict__ ym)
{
    const int bn = blockIdx.x >> 4, hd = blockIdx.x & 15;
    __shared__ unsigned short QK[2][128][64];      // Q, K; later aliased as P[128][128]
    __shared__ unsigned short Vt[64][128];         // V transposed [d][s']
    __shared__ float Sc[128][128];
    __shared__ float rsum[128];
    unsigned short (*Pb)[128] = (unsigned short (*)[128])QK;

    const int tid = threadIdx.x;
    const int w = tid >> 6, l = tid & 63, qd = l >> 4, r = l & 15;
    const size_t base = ((size_t)bn * 128) * 1024 + hd * 64;

    for (int idx = tid; idx < 1024; idx += 256) {   // 128 rows x 8 segs of 16B
        int row = idx >> 3, seg = idx & 7;
        *(uint4*)&QK[0][row][seg * 8] = *(const uint4*)&qm[base + (size_t)row * 1024 + seg * 8];
        *(uint4*)&QK[1][row][seg * 8] = *(const uint4*)&km[base + (size_t)row * 1024 + seg * 8];
    }
    for (int idx = tid; idx < 8192; idx += 256) {   // V transpose
        int s = idx >> 6, d = idx & 63;
        Vt[d][s] = vm[base + (size_t)s * 1024 + d];
    }
    __syncthreads();

    // S = Q K^T * 0.125 : wave w owns m-tiles {2w, 2w+1}, all 8 n-tiles
    for (int im = 0; im < 2; im++) {
        const int i = w * 2 + im;
        float4v acc[8];
        float4v zero = {0.f, 0.f, 0.f, 0.f};
        for (int j = 0; j < 8; j++) acc[j] = zero;
        for (int k0 = 0; k0 < 64; k0 += 32) {
            short8 af = *(const short8*)&QK[0][i * 16 + r][k0 + qd * 8];
            for (int j = 0; j < 8; j++) {
                short8 bf = *(const short8*)&QK[1][j * 16 + r][k0 + qd * 8];
                acc[j] = mfma16(af, bf, acc[j]);
            }
        }
        for (int j = 0; j < 8; j++)
            for (int t4 = 0; t4 < 4; t4++)
                Sc[i * 16 + qd * 4 + t4][j * 16 + r] = acc[j][t4] * 0.125f;
    }
    __syncthreads();

    // causal softmax (unnormalized exp, bf16 P), one thread per row
    if (tid < 128) {
        const int s = tid;
        float mx = -1e30f;
        for (int j = 0; j <= s; j++) mx = fmaxf(mx, Sc[s][j]);
        float sum = 0.f;
        for (int j = 0; j <= s; j++) {
            float e = __expf(Sc[s][j] - mx);
            sum += e;
            Pb[s][j] = f2b(e);
        }
        for (int j = s + 1; j < 128; j++) Pb[s][j] = 0;
        rsum[s] = 1.f / sum;
    }
    __syncthreads();

    // Y = (P V) * rsum : wave w owns m-tiles {2w,2w+1}, 4 n-tiles (d=64)
    for (int im = 0; im < 2; im++) {
        const int i = w * 2 + im;
        float4v acc[4];
        float4v zero = {0.f, 0.f, 0.f, 0.f};
        for (int j = 0; j < 4; j++) acc[j] = zero;
        for (int k0 = 0; k0 < 128; k0 += 32) {
            short8 af = *(const short8*)&Pb[i * 16 + r][k0 + qd * 8];
            for (int j = 0; j < 4; j++) {
                short8 bf = *(const short8*)&Vt[j * 16 + r][k0 + qd * 8];
                acc[j] = mfma16(af, bf, acc[j]);
            }
        }
        for (int j = 0; j < 4; j++)
            for (int t4 = 0; t4 < 4; t4++) {
                const int srow = i * 16 + qd * 4 + t4;
                ym[base + (size_t)srow * 1024 + j * 16 + r] = f2b(acc[j][t4] * rsum[srow]);
            }
    }
}

// ---------------------------------------------------------------------------
// Final: LN(x[bn,126,:]) @ head_W -> out[bn*32+a]. One block per bn.
// ---------------------------------------------------------------------------
__global__ __launch_bounds__(256) void final_kernel(
    const float* __restrict__ x, const float* __restrict__ lnw,
    const float* __restrict__ lnb, const float* __restrict__ headW,
    float* __restrict__ out)
{
    const int bn = blockIdx.x;
    const int tid = threadIdx.x;
    const float* xr = x + ((size_t)bn * 128 + 126) * 1024;
    float4 v = *(const float4*)&xr[tid * 4];
    float s  = v.x + v.y + v.z + v.w;
    float s2 = v.x * v.x + v.y * v.y + v.z * v.z + v.w * v.w;
    for (int o = 32; o > 0; o >>= 1) { s += __shfl_down(s, o); s2 += __shfl_down(s2, o); }
    __shared__ float ls[4], ls2[4];
    if ((tid & 63) == 0) { ls[tid >> 6] = s; ls2[tid >> 6] = s2; }
    __syncthreads();
    s  = ls[0] + ls[1] + ls[2] + ls[3];
    s2 = ls2[0] + ls2[1] + ls2[2] + ls2[3];
    float mean = s * (1.f / 1024.f);
    float var  = s2 * (1.f / 1024.f) - mean * mean;
    float inv  = rsqrtf(var + 1e-5f);
    __shared__ float hf[1024];
    float4 wv = *(const float4*)&lnw[tid * 4];
    float4 bv = *(const float4*)&lnb[tid * 4];
    hf[tid * 4 + 0] = (v.x - mean) * inv * wv.x + bv.x;
    hf[tid * 4 + 1] = (v.y - mean) * inv * wv.y + bv.y;
    hf[tid * 4 + 2] = (v.z - mean) * inv * wv.z + bv.z;
    hf[tid * 4 + 3] = (v.w - mean) * inv * wv.w + bv.w;
    __syncthreads();
    const int a = tid & 31, part = tid >> 5;          // 8 partials per output
    float sum = 0.f;
    for (int c = part * 128; c < (part + 1) * 128; c++)
        sum += hf[c] * headW[(size_t)c * 32 + a];
    __shared__ float red[256];
    red[tid] = sum;
    __syncthreads();
    if (part == 0) {
        float tot = 0.f;
        for (int p = 0; p < 8; p++) tot += red[p * 32 + a];
        out[(size_t)bn * 32 + a] = tot;
    }
}

// ---------------------------------------------------------------------------
extern "C" void kernel_launch(void* const* d_in, const int* in_sizes, int n_in,
                              void* d_out, int out_size, void* d_ws, size_t ws_size,
                              hipStream_t stream)
{
    const float* states    = (const float*)d_in[0];
    const float* actions   = (const float*)d_in[1];
    const int*   timesteps = (const int*)  d_in[2];
    const float* pos_emb   = (const float*)d_in[3];
    const float* gpe_tab   = (const float*)d_in[4];
    const float* seW  = (const float*)d_in[5];
    const float* seb  = (const float*)d_in[6];
    const float* aeW  = (const float*)d_in[7];
    const float* aeb  = (const float*)d_in[8];
    const float* ln1w = (const float*)d_in[9];
    const float* ln1b = (const float*)d_in[10];
    const float* Wq = (const float*)d_in[11];
    const float* bq = (const float*)d_in[12];
    const float* Wk = (const float*)d_in[13];
    const float* bk = (const float*)d_in[14];
    const float* Wv = (const float*)d_in[15];
    const float* bv = (const float*)d_in[16];
    const float* Wp = (const float*)d_in[17];
    const float* bp = (const float*)d_in[18];
    const float* ln2w = (const float*)d_in[19];
    const float* ln2b = (const float*)d_in[20];
    const float* W1 = (const float*)d_in[21];
    const float* b1 = (const float*)d_in[22];
    const float* W2 = (const float*)d_in[23];
    const float* b2 = (const float*)d_in[24];
    const float* lnfw  = (const float*)d_in[25];
    const float* lnfb  = (const float*)d_in[26];
    const float* headW = (const float*)d_in[27];

    char* ws = (char*)d_ws;
    const size_t MB = 1024 * 1024;
    float*          x   = (float*)ws;                               // 64 MB
    unsigned short* h   = (unsigned short*)(ws + 64 * MB);          // 32 MB
    unsigned short* qb  = (unsigned short*)(ws + 96 * MB);          // 32 MB
    unsigned short* kb  = (unsigned short*)(ws + 128 * MB);         // 32 MB
    unsigned short* vb  = (unsigned short*)(ws + 160 * MB);         // 32 MB
    unsigned short* yb  = (unsigned short*)(ws + 192 * MB);         // 32 MB
    unsigned short* ub  = (unsigned short*)(ws + 96 * MB);          // 128 MB (aliases q/k/v/y, dead by MLP)
    unsigned short* wqT = (unsigned short*)(ws + 224 * MB);         // 2 MB
    unsigned short* wkT = (unsigned short*)(ws + 226 * MB);
    unsigned short* wvT = (unsigned short*)(ws + 228 * MB);
    unsigned short* wpT = (unsigned short*)(ws + 230 * MB);
    unsigned short* w1T = (unsigned short*)(ws + 232 * MB);         // 8 MB
    unsigned short* w2T = (unsigned short*)(ws + 240 * MB);         // 8 MB  (total 248 MB)

    embed_kernel<<<dim3(8, 512), 256, 0, stream>>>(
        states, actions, timesteps, pos_emb, gpe_tab, seW, seb, aeW, aeb, x);

    for (int lyr = 0; lyr < 8; lyr++) {
        const size_t oC  = (size_t)lyr * 1024 * 1024;
        const size_t oC4 = (size_t)lyr * 1024 * 4096;
        transpose_kernel<<<dim3(32, 32),  256, 0, stream>>>(Wq + oC,  wqT, 1024, 1024);
        transpose_kernel<<<dim3(32, 32),  256, 0, stream>>>(Wk + oC,  wkT, 1024, 1024);
        transpose_kernel<<<dim3(32, 32),  256, 0, stream>>>(Wv + oC,  wvT, 1024, 1024);
        transpose_kernel<<<dim3(32, 32),  256, 0, stream>>>(Wp + oC,  wpT, 1024, 1024);
        transpose_kernel<<<dim3(128, 32), 256, 0, stream>>>(W1 + oC4, w1T, 1024, 4096);
        transpose_kernel<<<dim3(32, 128), 256, 0, stream>>>(W2 + oC4, w2T, 4096, 1024);

        ln_kernel<<<16384, 256, 0, stream>>>(x, ln1w + lyr * 1024, ln1b + lyr * 1024, h);
        gemm_kernel<0><<<dim3(8, 128), 256, 0, stream>>>(h, wqT, bq + lyr * 1024, nullptr, qb, 16384, 1024, 1024);
        gemm_kernel<0><<<dim3(8, 128), 256, 0, stream>>>(h, wkT, bk + lyr * 1024, nullptr, kb, 16384, 1024, 1024);
        gemm_kernel<0><<<dim3(8, 128), 256, 0, stream>>>(h, wvT, bv + lyr * 1024, nullptr, vb, 16384, 1024, 1024);
        attn_kernel<<<2048, 256, 0, stream>>>(qb, kb, vb, yb);
        gemm_kernel<2><<<dim3(8, 128), 256, 0, stream>>>(yb, wpT, bp + lyr * 1024, x, x, 16384, 1024, 1024);
        ln_kernel<<<16384, 256, 0, stream>>>(x, ln2w + lyr * 1024, ln2b + lyr * 1024, h);
        gemm_kernel<1><<<dim3(32, 128), 256, 0, stream>>>(h, w1T, b1 + lyr * 4096, nullptr, ub, 16384, 4096, 1024);
        gemm_kernel<2><<<dim3(8, 128), 256, 0, stream>>>(ub, w2T, b2 + lyr * 1024, x, x, 16384, 1024, 4096);
    }

    final_kernel<<<128, 256, 0, stream>>>(x, lnfw, lnfb, headW, (float*)d_out);
}

// Round 2
// 7752.895 us; speedup vs baseline: 2.2347x; 2.2347x over previous
//
#include <hip/hip_runtime.h>
#include <math.h>

// ---------------------------------------------------------------------------
// Decision-transformer forward on MI355X.
// B=8,T=64,N=16,DS=128,A=32,C=1024,H=16,L=8 -> BN=128, S=128, d=64, M=BN*S=16384
// Residual stream x: fp32. GEMM inputs: bf16 (fp32 accum via MFMA).
// R1 fix: ALL global stores are >=16B/lane lane-contiguous (scalar sub-line
// stores showed 64x write amplification: 8.53 GB WRITE_SIZE on MLP1 = 64M
// stores x 128B line each).
// ---------------------------------------------------------------------------

typedef float  float4v __attribute__((ext_vector_type(4)));
typedef short  short8  __attribute__((ext_vector_type(8)));

__device__ inline unsigned short f2b(float f) {           // fp32 -> bf16 (RNE)
    unsigned int u = __float_as_uint(f);
    u += 0x7fffu + ((u >> 16) & 1u);
    return (unsigned short)(u >> 16);
}
__device__ inline float gelu_f(float v) {                 // tanh-approx GELU
    return 0.5f * v * (1.0f + tanhf(0.7978845608028654f * (v + 0.044715f * v * v * v)));
}
__device__ inline float4v mfma16(short8 a, short8 b, float4v c) {
    return __builtin_amdgcn_mfma_f32_16x16x32_bf16(a, b, c, 0, 0, 0);
}
#define GLOAD_LDS16(gp, lp)                                                 \
    __builtin_amdgcn_global_load_lds(                                       \
        (__attribute__((address_space(1))) void*)(gp),                      \
        (__attribute__((address_space(3))) void*)(lp), 16, 0, 0)

// ---------------------------------------------------------------------------
// Embedding: x[bn*128+s][c] = token_embed + pos_emb[s] + global_pos_emb[ts]
// grid (8 col-tiles of 128, 512 row-tiles of 32), block 256. float4 stores.
// ---------------------------------------------------------------------------
__global__ __launch_bounds__(256) void embed_kernel(
    const float* __restrict__ states, const float* __restrict__ actions,
    const int* __restrict__ timesteps, const float* __restrict__ pos_emb,
    const float* __restrict__ gpe_tab, const float* __restrict__ seW,
    const float* __restrict__ seb, const float* __restrict__ aeW,
    const float* __restrict__ aeb, float* __restrict__ x)
{
    const int c0 = blockIdx.x * 128;
    const int m0 = blockIdx.y * 32;
    const int bn = m0 >> 7;
    const int b  = bn >> 4, n = bn & 15;
    const int s_base = m0 & 127;            // multiple of 32
    const int tid = threadIdx.x;

    __shared__ float st[16][128];           // 16 even-s rows (states)
    __shared__ float ac[16][32];            // 16 odd-s rows (actions)
    for (int idx = tid; idx < 16 * 128; idx += 256) {
        int rr = idx >> 7, ds = idx & 127;
        int t = (s_base >> 1) + rr;
        st[rr][ds] = states[(((size_t)b * 64 + t) * 16 + n) * 128 + ds];
    }
    for (int idx = tid; idx < 16 * 32; idx += 256) {
        int rr = idx >> 5, a = idx & 31;
        int t = (s_base >> 1) + rr;
        ac[rr][a] = actions[(((size_t)b * 64 + t) * 16 + n) * 32 + a];
    }
    __syncthreads();

    const int half = tid >> 7;              // 0: even s (state), 1: odd s (action)
    const int sub  = tid & 127;
    const int cg   = sub & 31;              // 4-col group within 128-col tile
    const int rg   = sub >> 5;              // 4-row group within 16 rows

    float acc[4][4];
    for (int i = 0; i < 4; i++) for (int j = 0; j < 4; j++) acc[i][j] = 0.f;

    if (half == 0) {
        for (int kk = 0; kk < 128; kk++) {
            float4 w4 = *(const float4*)&seW[(size_t)kk * 1024 + c0 + cg * 4];
            for (int r4 = 0; r4 < 4; r4++) {
                float sv = st[rg * 4 + r4][kk];
                acc[r4][0] += sv * w4.x; acc[r4][1] += sv * w4.y;
                acc[r4][2] += sv * w4.z; acc[r4][3] += sv * w4.w;
            }
        }
    } else {
        for (int kk = 0; kk < 32; kk++) {
            float4 w4 = *(const float4*)&aeW[(size_t)kk * 1024 + c0 + cg * 4];
            for (int r4 = 0; r4 < 4; r4++) {
                float sv = ac[rg * 4 + r4][kk];
                acc[r4][0] += sv * w4.x; acc[r4][1] += sv * w4.y;
                acc[r4][2] += sv * w4.z; acc[r4][3] += sv * w4.w;
            }
        }
    }
    const float* bias = half ? aeb : seb;
    float4 b4 = *(const float4*)&bias[c0 + cg * 4];
    for (int r4 = 0; r4 < 4; r4++) {
        int rr = rg * 4 + r4;
        int s  = s_base + rr * 2 + half;
        int t  = (s_base >> 1) + rr;
        int m  = bn * 128 + s;
        int ts = timesteps[b * 64 + t];
        float4 p4 = *(const float4*)&pos_emb[(size_t)s * 1024 + c0 + cg * 4];
        float4 g4 = *(const float4*)&gpe_tab[(size_t)ts * 1024 + c0 + cg * 4];
        float4 o;
        o.x = acc[r4][0] + b4.x + p4.x + g4.x;
        o.y = acc[r4][1] + b4.y + p4.y + g4.y;
        o.z = acc[r4][2] + b4.z + p4.z + g4.z;
        o.w = acc[r4][3] + b4.w + p4.w + g4.w;
        *(float4*)&x[(size_t)m * 1024 + c0 + cg * 4] = o;
    }
}

// ---------------------------------------------------------------------------
// Weight transpose + fp32->bf16:  src[K,N] f32  ->  dst[N,K] bf16
// 32(n) x 64(k) tiles; output stores are uint4 (8 bf16 along K = full lines).
// grid (N/32, K/64), block 256
// ---------------------------------------------------------------------------
__global__ __launch_bounds__(256) void transpose_kernel(
    const float* __restrict__ src, unsigned short* __restrict__ dst, int K, int N)
{
    __shared__ float tile[32][65];
    const int n0 = blockIdx.x * 32, k0 = blockIdx.y * 64;
    const int tid = threadIdx.x;
    const int nl = tid & 31, kl = tid >> 5;           // load: lanes contiguous in n
    for (int p = 0; p < 8; p++)
        tile[nl][p * 8 + kl] = src[(size_t)(k0 + p * 8 + kl) * N + n0 + nl];
    __syncthreads();
    const int n2 = tid >> 3, kseg = tid & 7;          // store: 8 bf16 per thread
    unsigned short o8[8];
    for (int u = 0; u < 8; u++) o8[u] = f2b(tile[n2][kseg * 8 + u]);
    *(uint4*)&dst[(size_t)(n0 + n2) * K + k0 + kseg * 8] = *(uint4*)o8;
}

// ---------------------------------------------------------------------------
// LayerNorm: x fp32 [rows,1024] -> out bf16. 2 rows/block, 8 elems/thread,
// 16B stores. grid rows/2, block 256.
// ---------------------------------------------------------------------------
__global__ __launch_bounds__(256) void ln_kernel(
    const float* __restrict__ x, const float* __restrict__ w,
    const float* __restrict__ b, unsigned short* __restrict__ out)
{
    const int tid = threadIdx.x;
    const int row = blockIdx.x * 2 + (tid >> 7);
    const int sub = tid & 127;
    const float* xr = x + (size_t)row * 1024 + sub * 8;
    float4 a = *(const float4*)xr;
    float4 c = *(const float4*)(xr + 4);
    float s  = a.x + a.y + a.z + a.w + c.x + c.y + c.z + c.w;
    float s2 = a.x*a.x + a.y*a.y + a.z*a.z + a.w*a.w
             + c.x*c.x + c.y*c.y + c.z*c.z + c.w*c.w;
    for (int o = 32; o > 0; o >>= 1) { s += __shfl_down(s, o); s2 += __shfl_down(s2, o); }
    __shared__ float ls[4], ls2[4];
    if ((tid & 63) == 0) { ls[tid >> 6] = s; ls2[tid >> 6] = s2; }
    __syncthreads();
    const int wp = (tid >> 7) * 2;
    s  = ls[wp] + ls[wp + 1];
    s2 = ls2[wp] + ls2[wp + 1];
    float mean = s * (1.f / 1024.f);
    float var  = s2 * (1.f / 1024.f) - mean * mean;
    float inv  = rsqrtf(var + 1e-5f);
    float4 wa = *(const float4*)&w[sub * 8];
    float4 wc = *(const float4*)&w[sub * 8 + 4];
    float4 ba = *(const float4*)&b[sub * 8];
    float4 bc = *(const float4*)&b[sub * 8 + 4];
    unsigned short o8[8];
    o8[0] = f2b((a.x - mean) * inv * wa.x + ba.x);
    o8[1] = f2b((a.y - mean) * inv * wa.y + ba.y);
    o8[2] = f2b((a.z - mean) * inv * wa.z + ba.z);
    o8[3] = f2b((a.w - mean) * inv * wa.w + ba.w);
    o8[4] = f2b((c.x - mean) * inv * wc.x + bc.x);
    o8[5] = f2b((c.y - mean) * inv * wc.y + bc.y);
    o8[6] = f2b((c.z - mean) * inv * wc.z + bc.z);
    o8[7] = f2b((c.w - mean) * inv * wc.w + bc.w);
    *(uint4*)&out[(size_t)row * 1024 + sub * 8] = *(uint4*)o8;
}

// ---------------------------------------------------------------------------
// GEMM: out[M,N] = A[M,K](bf16) @ Bt[N,K](bf16)^T + bias (+resid)
// 128x128 tile, BK=32, 4 waves, 16x16x32 MFMA, global_load_lds staging.
// Epilogue stages the tile in LDS then does full-line vector stores.
// MODE 0: bf16 = acc+bias   1: bf16 = gelu(acc+bias)   2: fp32 = acc+bias+resid
// ---------------------------------------------------------------------------
template <int MODE>
__global__ __launch_bounds__(256) void gemm_kernel(
    const unsigned short* __restrict__ A, const unsigned short* __restrict__ Bt,
    const float* __restrict__ bias, const float* __restrict__ resid,
    void* __restrict__ outp, int M, int N, int K)
{
    __shared__ unsigned short As[128][32];
    __shared__ unsigned short Bs[128][32];
    __shared__ __align__(16) char Osmem[32768];       // out staging (bf16 full / fp32 half)
    const int tid = threadIdx.x;
    const int w  = tid >> 6, l = tid & 63;
    const int wr = w >> 1, wc = w & 1;
    const int qd = l >> 4, r = l & 15;
    const int m0 = blockIdx.y * 128, n0 = blockIdx.x * 128;

    const unsigned short* Ab = A  + (size_t)m0 * K;
    const unsigned short* Bb = Bt + (size_t)n0 * K;

    float4v acc[4][4];
    float4v zero = {0.f, 0.f, 0.f, 0.f};
    for (int i = 0; i < 4; i++) for (int j = 0; j < 4; j++) acc[i][j] = zero;

    const int ra0 = tid >> 2,         ca0 = (tid & 3) * 8;
    const int ra1 = (tid + 256) >> 2, ca1 = ((tid + 256) & 3) * 8;

    for (int k0 = 0; k0 < K; k0 += 32) {
        GLOAD_LDS16(Ab + (size_t)ra0 * K + k0 + ca0, &As[ra0][ca0]);
        GLOAD_LDS16(Ab + (size_t)ra1 * K + k0 + ca1, &As[ra1][ca1]);
        GLOAD_LDS16(Bb + (size_t)ra0 * K + k0 + ca0, &Bs[ra0][ca0]);
        GLOAD_LDS16(Bb + (size_t)ra1 * K + k0 + ca1, &Bs[ra1][ca1]);
        __syncthreads();
        short8 af[4], bfv[4];
        for (int i = 0; i < 4; i++) af[i]  = *(const short8*)&As[wr * 64 + i * 16 + r][qd * 8];
        for (int j = 0; j < 4; j++) bfv[j] = *(const short8*)&Bs[wc * 64 + j * 16 + r][qd * 8];
        for (int i = 0; i < 4; i++)
            for (int j = 0; j < 4; j++)
                acc[i][j] = mfma16(af[i], bfv[j], acc[i][j]);
        __syncthreads();
    }

    // C/D layout: col = lane&15, row = (lane>>4)*4 + reg  [m89/m91]
    if (MODE != 2) {
        unsigned short (*Ob)[128] = (unsigned short (*)[128])Osmem;
        for (int i = 0; i < 4; i++) {
            const int rl = wr * 64 + i * 16 + qd * 4;
            for (int j = 0; j < 4; j++) {
                const int cl = wc * 64 + j * 16 + r;
                const float bv = bias[n0 + cl];
                for (int t4 = 0; t4 < 4; t4++) {
                    float v = acc[i][j][t4] + bv;
                    if (MODE == 1) v = gelu_f(v);
                    Ob[rl + t4][cl] = f2b(v);
                }
            }
        }
        __syncthreads();
        unsigned short* op = (unsigned short*)outp;
        for (int it = 0; it < 8; it++) {
            const int idx = it * 256 + tid;
            const int rl = idx >> 4, seg = idx & 15;
            *(uint4*)&op[(size_t)(m0 + rl) * N + n0 + seg * 8] = *(uint4*)&Ob[rl][seg * 8];
        }
    } else {
        float (*Of)[128] = (float (*)[128])Osmem;     // 64 rows per pass
        float* op = (float*)outp;
        for (int p = 0; p < 2; p++) {
            if (wr == p) {
                for (int i = 0; i < 4; i++) {
                    const int rl = i * 16 + qd * 4;
                    for (int j = 0; j < 4; j++) {
                        const int cl = wc * 64 + j * 16 + r;
                        const float bv = bias[n0 + cl];
                        for (int t4 = 0; t4 < 4; t4++)
                            Of[rl + t4][cl] = acc[i][j][t4] + bv;
                    }
                }
            }
            __syncthreads();
            for (int it = 0; it < 8; it++) {
                const int idx = it * 256 + tid;
                const int rl = idx >> 5, c4 = (idx & 31) * 4;
                const size_t go = (size_t)(m0 + p * 64 + rl) * N + n0 + c4;
                float4 rv = *(const float4*)&resid[go];
                float4 ov = *(float4*)&Of[rl][c4];
                ov.x += rv.x; ov.y += rv.y; ov.z += rv.z; ov.w += rv.w;
                *(float4*)&op[go] = ov;
            }
            __syncthreads();
        }
    }
}

// ---------------------------------------------------------------------------
// Attention: one block per (bn, head). S=128, d=64. Causal softmax.
// Y staged into dead Vt buffer, then full-line vector stores.
// ---------------------------------------------------------------------------
__global__ __launch_bounds__(256) void attn_kernel(
    const unsigned short* __restrict__ qm, const unsigned short* __restrict__ km,
    const unsigned short* __restrict__ vm, unsigned short* __restrict__ ym)
{
    const int bn = blockIdx.x >> 4, hd = blockIdx.x & 15;
    __shared__ unsigned short QK[2][128][64];      // Q, K; later aliased as P[128][128]
    __shared__ unsigned short Vt[64][128];         // V transposed; later Y staging
    __shared__ float Sc[128][128];
    __shared__ float rsum[128];
    unsigned short (*Pb)[128] = (unsigned short (*)[128])QK;

    const int tid = threadIdx.x;
    const int w = tid >> 6, l = tid & 63, qd = l >> 4, r = l & 15;
    const size_t base = ((size_t)bn * 128) * 1024 + hd * 64;

    for (int idx = tid; idx < 1024; idx += 256) {
        int row = idx >> 3, seg = idx & 7;
        *(uint4*)&QK[0][row][seg * 8] = *(const uint4*)&qm[base + (size_t)row * 1024 + seg * 8];
        *(uint4*)&QK[1][row][seg * 8] = *(const uint4*)&km[base + (size_t)row * 1024 + seg * 8];
    }
    for (int idx = tid; idx < 8192; idx += 256) {
        int s = idx >> 6, d = idx & 63;
        Vt[d][s] = vm[base + (size_t)s * 1024 + d];
    }
    __syncthreads();

    // S = Q K^T * 0.125
    for (int im = 0; im < 2; im++) {
        const int i = w * 2 + im;
        float4v acc[8];
        float4v zero = {0.f, 0.f, 0.f, 0.f};
        for (int j = 0; j < 8; j++) acc[j] = zero;
        for (int k0 = 0; k0 < 64; k0 += 32) {
            short8 af = *(const short8*)&QK[0][i * 16 + r][k0 + qd * 8];
            for (int j = 0; j < 8; j++) {
                short8 bf = *(const short8*)&QK[1][j * 16 + r][k0 + qd * 8];
                acc[j] = mfma16(af, bf, acc[j]);
            }
        }
        for (int j = 0; j < 8; j++)
            for (int t4 = 0; t4 < 4; t4++)
                Sc[i * 16 + qd * 4 + t4][j * 16 + r] = acc[j][t4] * 0.125f;
    }
    __syncthreads();

    // causal softmax (unnormalized exp, bf16 P)
    if (tid < 128) {
        const int s = tid;
        float mx = -1e30f;
        for (int j = 0; j <= s; j++) mx = fmaxf(mx, Sc[s][j]);
        float sum = 0.f;
        for (int j = 0; j <= s; j++) {
            float e = __expf(Sc[s][j] - mx);
            sum += e;
            Pb[s][j] = f2b(e);
        }
        for (int j = s + 1; j < 128; j++) Pb[s][j] = 0;
        rsum[s] = 1.f / sum;
    }
    __syncthreads();

    // Y = (P V) * rsum
    float4v acc2[2][4];
    {
        float4v zero = {0.f, 0.f, 0.f, 0.f};
        for (int im = 0; im < 2; im++) for (int j = 0; j < 4; j++) acc2[im][j] = zero;
    }
    for (int im = 0; im < 2; im++) {
        const int i = w * 2 + im;
        for (int k0 = 0; k0 < 128; k0 += 32) {
            short8 af = *(const short8*)&Pb[i * 16 + r][k0 + qd * 8];
            for (int j = 0; j < 4; j++) {
                short8 bf = *(const short8*)&Vt[j * 16 + r][k0 + qd * 8];
                acc2[im][j] = mfma16(af, bf, acc2[im][j]);
            }
        }
    }
    __syncthreads();                               // all waves done reading Vt
    unsigned short (*Ys)[64] = (unsigned short (*)[64])Vt;
    for (int im = 0; im < 2; im++) {
        const int i = w * 2 + im;
        for (int j = 0; j < 4; j++)
            for (int t4 = 0; t4 < 4; t4++) {
                const int srow = i * 16 + qd * 4 + t4;
                Ys[srow][j * 16 + r] = f2b(acc2[im][j][t4] * rsum[srow]);
            }
    }
    __syncthreads();
    for (int it = 0; it < 4; it++) {
        const int idx = it * 256 + tid;
        const int row = idx >> 3, seg = idx & 7;
        *(uint4*)&ym[base + (size_t)row * 1024 + seg * 8] = *(uint4*)&Ys[row][seg * 8];
    }
}

// ---------------------------------------------------------------------------
// Final: LN(x[bn,126,:]) @ head_W -> out[bn*32+a]. One block per bn.
// ---------------------------------------------------------------------------
__global__ __launch_bounds__(256) void final_kernel(
    const float* __restrict__ x, const float* __restrict__ lnw,
    const float* __restrict__ lnb, const float* __restrict__ headW,
    float* __restrict__ out)
{
    const int bn = blockIdx.x;
    const int tid = threadIdx.x;
    const float* xr = x + ((size_t)bn * 128 + 126) * 1024;
    float4 v = *(const float4*)&xr[tid * 4];
    float s  = v.x + v.y + v.z + v.w;
    float s2 = v.x * v.x + v.y * v.y + v.z * v.z + v.w * v.w;
    for (int o = 32; o > 0; o >>= 1) { s += __shfl_down(s, o); s2 += __shfl_down(s2, o); }
    __shared__ float ls[4], ls2[4];
    if ((tid & 63) == 0) { ls[tid >> 6] = s; ls2[tid >> 6] = s2; }
    __syncthreads();
    s  = ls[0] + ls[1] + ls[2] + ls[3];
    s2 = ls2[0] + ls2[1] + ls2[2] + ls2[3];
    float mean = s * (1.f / 1024.f);
    float var  = s2 * (1.f / 1024.f) - mean * mean;
    float inv  = rsqrtf(var + 1e-5f);
    __shared__ float hf[1024];
    float4 wv = *(const float4*)&lnw[tid * 4];
    float4 bv = *(const float4*)&lnb[tid * 4];
    hf[tid * 4 + 0] = (v.x - mean) * inv * wv.x + bv.x;
    hf[tid * 4 + 1] = (v.y - mean) * inv * wv.y + bv.y;
    hf[tid * 4 + 2] = (v.z - mean) * inv * wv.z + bv.z;
    hf[tid * 4 + 3] = (v.w - mean) * inv * wv.w + bv.w;
    __syncthreads();
    const int a = tid & 31, part = tid >> 5;
    float sum = 0.f;
    for (int c = part * 128; c < (part + 1) * 128; c++)
        sum += hf[c] * headW[(size_t)c * 32 + a];
    __shared__ float red[256];
    red[tid] = sum;
    __syncthreads();
    if (part == 0) {
        float tot = 0.f;
        for (int p = 0; p < 8; p++) tot += red[p * 32 + a];
        out[(size_t)bn * 32 + a] = tot;
    }
}

// ---------------------------------------------------------------------------
extern "C" void kernel_launch(void* const* d_in, const int* in_sizes, int n_in,
                              void* d_out, int out_size, void* d_ws, size_t ws_size,
                              hipStream_t stream)
{
    const float* states    = (const float*)d_in[0];
    const float* actions   = (const float*)d_in[1];
    const int*   timesteps = (const int*)  d_in[2];
    const float* pos_emb   = (const float*)d_in[3];
    const float* gpe_tab   = (const float*)d_in[4];
    const float* seW  = (const float*)d_in[5];
    const float* seb  = (const float*)d_in[6];
    const float* aeW  = (const float*)d_in[7];
    const float* aeb  = (const float*)d_in[8];
    const float* ln1w = (const float*)d_in[9];
    const float* ln1b = (const float*)d_in[10];
    const float* Wq = (const float*)d_in[11];
    const float* bq = (const float*)d_in[12];
    const float* Wk = (const float*)d_in[13];
    const float* bk = (const float*)d_in[14];
    const float* Wv = (const float*)d_in[15];
    const float* bv = (const float*)d_in[16];
    const float* Wp = (const float*)d_in[17];
    const float* bp = (const float*)d_in[18];
    const float* ln2w = (const float*)d_in[19];
    const float* ln2b = (const float*)d_in[20];
    const float* W1 = (const float*)d_in[21];
    const float* b1 = (const float*)d_in[22];
    const float* W2 = (const float*)d_in[23];
    const float* b2 = (const float*)d_in[24];
    const float* lnfw  = (const float*)d_in[25];
    const float* lnfb  = (const float*)d_in[26];
    const float* headW = (const float*)d_in[27];

    char* ws = (char*)d_ws;
    const size_t MB = 1024 * 1024;
    float*          x   = (float*)ws;                               // 64 MB
    unsigned short* h   = (unsigned short*)(ws + 64 * MB);          // 32 MB
    unsigned short* qb  = (unsigned short*)(ws + 96 * MB);          // 32 MB
    unsigned short* kb  = (unsigned short*)(ws + 128 * MB);         // 32 MB
    unsigned short* vb  = (unsigned short*)(ws + 160 * MB);         // 32 MB
    unsigned short* yb  = (unsigned short*)(ws + 192 * MB);         // 32 MB
    unsigned short* ub  = (unsigned short*)(ws + 96 * MB);          // 128 MB (aliases q/k/v/y)
    unsigned short* wqT = (unsigned short*)(ws + 224 * MB);         // 2 MB
    unsigned short* wkT = (unsigned short*)(ws + 226 * MB);
    unsigned short* wvT = (unsigned short*)(ws + 228 * MB);
    unsigned short* wpT = (unsigned short*)(ws + 230 * MB);
    unsigned short* w1T = (unsigned short*)(ws + 232 * MB);         // 8 MB
    unsigned short* w2T = (unsigned short*)(ws + 240 * MB);         // 8 MB  (total 248 MB)

    embed_kernel<<<dim3(8, 512), 256, 0, stream>>>(
        states, actions, timesteps, pos_emb, gpe_tab, seW, seb, aeW, aeb, x);

    for (int lyr = 0; lyr < 8; lyr++) {
        const size_t oC  = (size_t)lyr * 1024 * 1024;
        const size_t oC4 = (size_t)lyr * 1024 * 4096;
        transpose_kernel<<<dim3(32, 16),  256, 0, stream>>>(Wq + oC,  wqT, 1024, 1024);
        transpose_kernel<<<dim3(32, 16),  256, 0, stream>>>(Wk + oC,  wkT, 1024, 1024);
        transpose_kernel<<<dim3(32, 16),  256, 0, stream>>>(Wv + oC,  wvT, 1024, 1024);
        transpose_kernel<<<dim3(32, 16),  256, 0, stream>>>(Wp + oC,  wpT, 1024, 1024);
        transpose_kernel<<<dim3(128, 16), 256, 0, stream>>>(W1 + oC4, w1T, 1024, 4096);
        transpose_kernel<<<dim3(32, 64),  256, 0, stream>>>(W2 + oC4, w2T, 4096, 1024);

        ln_kernel<<<8192, 256, 0, stream>>>(x, ln1w + lyr * 1024, ln1b + lyr * 1024, h);
        gemm_kernel<0><<<dim3(8, 128), 256, 0, stream>>>(h, wqT, bq + lyr * 1024, nullptr, qb, 16384, 1024, 1024);
        gemm_kernel<0><<<dim3(8, 128), 256, 0, stream>>>(h, wkT, bk + lyr * 1024, nullptr, kb, 16384, 1024, 1024);
        gemm_kernel<0><<<dim3(8, 128), 256, 0, stream>>>(h, wvT, bv + lyr * 1024, nullptr, vb, 16384, 1024, 1024);
        attn_kernel<<<2048, 256, 0, stream>>>(qb, kb, vb, yb);
        gemm_kernel<2><<<dim3(8, 128), 256, 0, stream>>>(yb, wpT, bp + lyr * 1024, x, x, 16384, 1024, 1024);
        ln_kernel<<<8192, 256, 0, stream>>>(x, ln2w + lyr * 1024, ln2b + lyr * 1024, h);
        gemm_kernel<1><<<dim3(32, 128), 256, 0, stream>>>(h, w1T, b1 + lyr * 4096, nullptr, ub, 16384, 4096, 1024);
        gemm_kernel<2><<<dim3(8, 128), 256, 0, stream>>>(ub, w2T, b2 + lyr * 1024, x, x, 16384, 1024, 4096);
    }

    final_kernel<<<128, 256, 0, stream>>>(x, lnfw, lnfb, headW, (float*)d_out);
}

// Round 3
// 6825.073 us; speedup vs baseline: 2.5385x; 1.1359x over previous
//
#include <hip/hip_runtime.h>
#include <math.h>

// ---------------------------------------------------------------------------
// Decision-transformer forward on MI355X.
// B=8,T=64,N=16,DS=128,A=32,C=1024,H=16,L=8 -> BN=128, S=128, d=64, M=BN*S=16384
// R2: coalesced stores (64x write-amp fix).
// R3: sigmoid-form fast GELU; GEMM epilogue LDS-staging aliases As/Bs (48->32KB,
//     3->5 blocks/CU) with XOR-swizzle (kills 8-way epilogue write conflicts);
//     attention rework (coalesced V, swizzled tiles, parallel softmax);
//     last-layer trimming (only token 126 feeds the head -> proj/ln2/MLP of
//     layer 7 run on 128 rows).
// ---------------------------------------------------------------------------

typedef float  float4v __attribute__((ext_vector_type(4)));
typedef short  short8  __attribute__((ext_vector_type(8)));

__device__ inline unsigned short f2b(float f) {           // fp32 -> bf16 (RNE)
    unsigned int u = __float_as_uint(f);
    u += 0x7fffu + ((u >> 16) & 1u);
    return (unsigned short)(u >> 16);
}
// tanh-approx GELU, exact sigmoid identity: v - v/(exp(2z)+1), z = 0.79788(v+0.044715 v^3)
__device__ inline float gelu_f(float v) {
    float z2 = 1.5957691216057308f * v + 0.07135481282377437f * v * v * v;
    return v - v / (__expf(z2) + 1.0f);
}
__device__ inline float4v mfma16(short8 a, short8 b, float4v c) {
    return __builtin_amdgcn_mfma_f32_16x16x32_bf16(a, b, c, 0, 0, 0);
}
#define GLOAD_LDS16(gp, lp)                                                 \
    __builtin_amdgcn_global_load_lds(                                       \
        (__attribute__((address_space(1))) void*)(gp),                      \
        (__attribute__((address_space(3))) void*)(lp), 16, 0, 0)

// ---------------------------------------------------------------------------
// Embedding (unchanged from R2)
// ---------------------------------------------------------------------------
__global__ __launch_bounds__(256) void embed_kernel(
    const float* __restrict__ states, const float* __restrict__ actions,
    const int* __restrict__ timesteps, const float* __restrict__ pos_emb,
    const float* __restrict__ gpe_tab, const float* __restrict__ seW,
    const float* __restrict__ seb, const float* __restrict__ aeW,
    const float* __restrict__ aeb, float* __restrict__ x)
{
    const int c0 = blockIdx.x * 128;
    const int m0 = blockIdx.y * 32;
    const int bn = m0 >> 7;
    const int b  = bn >> 4, n = bn & 15;
    const int s_base = m0 & 127;
    const int tid = threadIdx.x;

    __shared__ float st[16][128];
    __shared__ float ac[16][32];
    for (int idx = tid; idx < 16 * 128; idx += 256) {
        int rr = idx >> 7, ds = idx & 127;
        int t = (s_base >> 1) + rr;
        st[rr][ds] = states[(((size_t)b * 64 + t) * 16 + n) * 128 + ds];
    }
    for (int idx = tid; idx < 16 * 32; idx += 256) {
        int rr = idx >> 5, a = idx & 31;
        int t = (s_base >> 1) + rr;
        ac[rr][a] = actions[(((size_t)b * 64 + t) * 16 + n) * 32 + a];
    }
    __syncthreads();

    const int half = tid >> 7;
    const int sub  = tid & 127;
    const int cg   = sub & 31;
    const int rg   = sub >> 5;

    float acc[4][4];
    for (int i = 0; i < 4; i++) for (int j = 0; j < 4; j++) acc[i][j] = 0.f;

    if (half == 0) {
        for (int kk = 0; kk < 128; kk++) {
            float4 w4 = *(const float4*)&seW[(size_t)kk * 1024 + c0 + cg * 4];
            for (int r4 = 0; r4 < 4; r4++) {
                float sv = st[rg * 4 + r4][kk];
                acc[r4][0] += sv * w4.x; acc[r4][1] += sv * w4.y;
                acc[r4][2] += sv * w4.z; acc[r4][3] += sv * w4.w;
            }
        }
    } else {
        for (int kk = 0; kk < 32; kk++) {
            float4 w4 = *(const float4*)&aeW[(size_t)kk * 1024 + c0 + cg * 4];
            for (int r4 = 0; r4 < 4; r4++) {
                float sv = ac[rg * 4 + r4][kk];
                acc[r4][0] += sv * w4.x; acc[r4][1] += sv * w4.y;
                acc[r4][2] += sv * w4.z; acc[r4][3] += sv * w4.w;
            }
        }
    }
    const float* bias = half ? aeb : seb;
    float4 b4 = *(const float4*)&bias[c0 + cg * 4];
    for (int r4 = 0; r4 < 4; r4++) {
        int rr = rg * 4 + r4;
        int s  = s_base + rr * 2 + half;
        int t  = (s_base >> 1) + rr;
        int m  = bn * 128 + s;
        int ts = timesteps[b * 64 + t];
        float4 p4 = *(const float4*)&pos_emb[(size_t)s * 1024 + c0 + cg * 4];
        float4 g4 = *(const float4*)&gpe_tab[(size_t)ts * 1024 + c0 + cg * 4];
        float4 o;
        o.x = acc[r4][0] + b4.x + p4.x + g4.x;
        o.y = acc[r4][1] + b4.y + p4.y + g4.y;
        o.z = acc[r4][2] + b4.z + p4.z + g4.z;
        o.w = acc[r4][3] + b4.w + p4.w + g4.w;
        *(float4*)&x[(size_t)m * 1024 + c0 + cg * 4] = o;
    }
}

// ---------------------------------------------------------------------------
// Weight transpose + fp32->bf16:  src[K,N] f32 -> dst[N,K] bf16 (R2, unchanged)
// ---------------------------------------------------------------------------
__global__ __launch_bounds__(256) void transpose_kernel(
    const float* __restrict__ src, unsigned short* __restrict__ dst, int K, int N)
{
    __shared__ float tile[32][65];
    const int n0 = blockIdx.x * 32, k0 = blockIdx.y * 64;
    const int tid = threadIdx.x;
    const int nl = tid & 31, kl = tid >> 5;
    for (int p = 0; p < 8; p++)
        tile[nl][p * 8 + kl] = src[(size_t)(k0 + p * 8 + kl) * N + n0 + nl];
    __syncthreads();
    const int n2 = tid >> 3, kseg = tid & 7;
    unsigned short o8[8];
    for (int u = 0; u < 8; u++) o8[u] = f2b(tile[n2][kseg * 8 + u]);
    *(uint4*)&dst[(size_t)(n0 + n2) * K + k0 + kseg * 8] = *(uint4*)o8;
}

// ---------------------------------------------------------------------------
// LayerNorm: gathered-row variant. xrow = x + row*xrs; out row compact (1024).
// grid = rows/2, block 256.
// ---------------------------------------------------------------------------
__global__ __launch_bounds__(256) void ln_kernel(
    const float* __restrict__ x, long xrs, const float* __restrict__ w,
    const float* __restrict__ b, unsigned short* __restrict__ out)
{
    const int tid = threadIdx.x;
    const int row = blockIdx.x * 2 + (tid >> 7);
    const int sub = tid & 127;
    const float* xr = x + (size_t)row * xrs + sub * 8;
    float4 a = *(const float4*)xr;
    float4 c = *(const float4*)(xr + 4);
    float s  = a.x + a.y + a.z + a.w + c.x + c.y + c.z + c.w;
    float s2 = a.x*a.x + a.y*a.y + a.z*a.z + a.w*a.w
             + c.x*c.x + c.y*c.y + c.z*c.z + c.w*c.w;
    for (int o = 32; o > 0; o >>= 1) { s += __shfl_down(s, o); s2 += __shfl_down(s2, o); }
    __shared__ float ls[4], ls2[4];
    if ((tid & 63) == 0) { ls[tid >> 6] = s; ls2[tid >> 6] = s2; }
    __syncthreads();
    const int wp = (tid >> 7) * 2;
    s  = ls[wp] + ls[wp + 1];
    s2 = ls2[wp] + ls2[wp + 1];
    float mean = s * (1.f / 1024.f);
    float var  = s2 * (1.f / 1024.f) - mean * mean;
    float inv  = rsqrtf(var + 1e-5f);
    float4 wa = *(const float4*)&w[sub * 8];
    float4 wc = *(const float4*)&w[sub * 8 + 4];
    float4 ba = *(const float4*)&b[sub * 8];
    float4 bc = *(const float4*)&b[sub * 8 + 4];
    unsigned short o8[8];
    o8[0] = f2b((a.x - mean) * inv * wa.x + ba.x);
    o8[1] = f2b((a.y - mean) * inv * wa.y + ba.y);
    o8[2] = f2b((a.z - mean) * inv * wa.z + ba.z);
    o8[3] = f2b((a.w - mean) * inv * wa.w + ba.w);
    o8[4] = f2b((c.x - mean) * inv * wc.x + bc.x);
    o8[5] = f2b((c.y - mean) * inv * wc.y + bc.y);
    o8[6] = f2b((c.z - mean) * inv * wc.z + bc.z);
    o8[7] = f2b((c.w - mean) * inv * wc.w + bc.w);
    *(uint4*)&out[(size_t)row * 1024 + sub * 8] = *(uint4*)o8;
}

// ---------------------------------------------------------------------------
// GEMM: out[M,N] = A @ Bt^T + bias (+resid). 128x128 tile, BK=32, 4 waves.
// A row stride = Ars (elements), out/resid row stride = Ors (supports gather).
// LDS 32KB total: K-loop As/Bs (16KB); epilogue staging ALIASES it (swizzled).
// MODE 0: bf16 = acc+bias   1: bf16 = gelu(acc+bias)   2: fp32 = acc+bias+resid
// ---------------------------------------------------------------------------
template <int MODE>
__global__ __launch_bounds__(256) void gemm_kernel(
    const unsigned short* __restrict__ A, const unsigned short* __restrict__ Bt,
    const float* __restrict__ bias, const float* __restrict__ resid,
    void* __restrict__ outp, int N, int K, long Ars, long Ors)
{
    __shared__ __align__(16) char smem[32768];
    unsigned short* As = (unsigned short*)smem;            // [128][32] linear
    unsigned short* Bs = (unsigned short*)(smem + 16384);
    const int tid = threadIdx.x;
    const int w  = tid >> 6, l = tid & 63;
    const int wr = w >> 1, wc = w & 1;
    const int qd = l >> 4, r = l & 15;
    const int m0 = blockIdx.y * 128, n0 = blockIdx.x * 128;

    const unsigned short* Ab = A  + (size_t)m0 * Ars;
    const unsigned short* Bb = Bt + (size_t)n0 * K;

    float4v acc[4][4];
    float4v zero = {0.f, 0.f, 0.f, 0.f};
    for (int i = 0; i < 4; i++) for (int j = 0; j < 4; j++) acc[i][j] = zero;

    const int ra0 = tid >> 2,  ca = (tid & 3) * 8;   // linear 16B/lane staging
    const int ra1 = ra0 + 64;

    for (int k0 = 0; k0 < K; k0 += 32) {
        GLOAD_LDS16(Ab + (size_t)ra0 * Ars + k0 + ca, As + tid * 8);
        GLOAD_LDS16(Ab + (size_t)ra1 * Ars + k0 + ca, As + (256 + tid) * 8);
        GLOAD_LDS16(Bb + (size_t)ra0 * K   + k0 + ca, Bs + tid * 8);
        GLOAD_LDS16(Bb + (size_t)ra1 * K   + k0 + ca, Bs + (256 + tid) * 8);
        __syncthreads();
        short8 af[4], bfv[4];
        for (int i = 0; i < 4; i++) af[i]  = *(const short8*)(As + (wr*64 + i*16 + r)*32 + qd*8);
        for (int j = 0; j < 4; j++) bfv[j] = *(const short8*)(Bs + (wc*64 + j*16 + r)*32 + qd*8);
        for (int i = 0; i < 4; i++)
            for (int j = 0; j < 4; j++)
                acc[i][j] = mfma16(af[i], bfv[j], acc[i][j]);
        __syncthreads();
    }

    // epilogue. C/D layout: col = lane&15, row = (lane>>4)*4 + reg [m89/m91]
    if (MODE != 2) {
        unsigned short* Ob = (unsigned short*)smem;        // [128]x16 slots, swizzled
        for (int i = 0; i < 4; i++) {
            for (int j = 0; j < 4; j++) {
                const int cl = wc * 64 + j * 16 + r;
                const float bv = bias[n0 + cl];
                for (int t4 = 0; t4 < 4; t4++) {
                    const int rl = wr * 64 + i * 16 + qd * 4 + t4;
                    float v = acc[i][j][t4] + bv;
                    if (MODE == 1) v = gelu_f(v);
                    Ob[rl * 128 + (((cl >> 3) ^ (rl & 15)) << 3) + (cl & 7)] = f2b(v);
                }
            }
        }
        __syncthreads();
        unsigned short* op = (unsigned short*)outp;
        for (int it = 0; it < 8; it++) {
            const int idx = it * 256 + tid;
            const int rl = idx >> 4, seg = idx & 15;
            *(uint4*)&op[(size_t)(m0 + rl) * Ors + n0 + seg * 8] =
                *(uint4*)&Ob[rl * 128 + ((seg ^ (rl & 15)) << 3)];
        }
    } else {
        float* Of = (float*)smem;                          // [64]x32 slots, swizzled
        float* op = (float*)outp;
        for (int p = 0; p < 2; p++) {
            if (wr == p) {
                for (int i = 0; i < 4; i++) {
                    for (int j = 0; j < 4; j++) {
                        const int cl = wc * 64 + j * 16 + r;
                        const float bv = bias[n0 + cl];
                        for (int t4 = 0; t4 < 4; t4++) {
                            const int lr = i * 16 + qd * 4 + t4;
                            Of[lr * 128 + (((cl >> 2) ^ (lr & 31)) << 2) + (cl & 3)] =
                                acc[i][j][t4] + bv;
                        }
                    }
                }
            }
            __syncthreads();
            for (int it = 0; it < 8; it++) {
                const int idx = it * 256 + tid;
                const int lr = idx >> 5, c4 = idx & 31;
                const size_t go = (size_t)(m0 + p * 64 + lr) * Ors + n0 + c4 * 4;
                float4 rv = *(const float4*)&resid[go];
                float4 ov = *(const float4*)&Of[lr * 128 + ((c4 ^ (lr & 31)) << 2)];
                ov.x += rv.x; ov.y += rv.y; ov.z += rv.z; ov.w += rv.w;
                *(float4*)&op[go] = ov;
            }
            __syncthreads();
        }
    }
}

// ---------------------------------------------------------------------------
// Attention: one block per (bn, head). S=128, d=64. Causal.
// All LDS tiles XOR-swizzled in 16B units for bank balance. Coalesced V load
// + LDS transpose. Softmax: 2 threads/row, float4, __expf.
// LDS: QK/P 32K + Vt 16K + Sc/Vs/Ys 64K + red 2.5K = ~115KB (1 block/CU).
// ---------------------------------------------------------------------------
__global__ __launch_bounds__(256) void attn_kernel(
    const unsigned short* __restrict__ qm, const unsigned short* __restrict__ km,
    const unsigned short* __restrict__ vm, unsigned short* __restrict__ ym)
{
    const int bn = blockIdx.x >> 4, hd = blockIdx.x & 15;
    __shared__ __align__(16) unsigned short QK[2][128 * 64]; // swizzle mask row&7
    __shared__ __align__(16) unsigned short Vt[64 * 128];    // swizzle mask row&15
    __shared__ __align__(16) float Sc[128 * 128];            // swizzle mask row&31
    __shared__ float pmax[2][128], psum[2][128], rsum[128];

    const int tid = threadIdx.x;
    const int w = tid >> 6, l = tid & 63, qd = l >> 4, r = l & 15;
    const size_t base = ((size_t)bn * 128) * 1024 + (size_t)hd * 64;

    unsigned short* Vs = (unsigned short*)Sc;                // [128][64] linear (temp)
    for (int idx = tid; idx < 1024; idx += 256) {
        int row = idx >> 3, seg = idx & 7;
        int sw = (seg ^ (row & 7)) << 3;
        *(uint4*)&QK[0][row * 64 + sw] = *(const uint4*)&qm[base + (size_t)row * 1024 + seg * 8];
        *(uint4*)&QK[1][row * 64 + sw] = *(const uint4*)&km[base + (size_t)row * 1024 + seg * 8];
        *(uint4*)&Vs[row * 64 + seg * 8] = *(const uint4*)&vm[base + (size_t)row * 1024 + seg * 8];
    }
    __syncthreads();

    // build Vt[d][s] (swizzled) from Vs
    for (int idx = tid; idx < 1024; idx += 256) {
        int d = idx & 63, sg = idx >> 6;                     // sg wave-uniform
        unsigned short tmp[8];
        for (int u = 0; u < 8; u++) tmp[u] = Vs[(sg * 8 + u) * 64 + d];
        *(uint4*)&Vt[d * 128 + ((sg ^ (d & 15)) << 3)] = *(uint4*)tmp;
    }

    // S = Q K^T * 0.125 ; wave w owns m-tiles {2w, 2w+1}
    float4v accS[2][8];
    { float4v z = {0,0,0,0}; for (int a = 0; a < 2; a++) for (int j = 0; j < 8; j++) accS[a][j] = z; }
    for (int im = 0; im < 2; im++) {
        const int i = w * 2 + im;
        const int rowA = i * 16 + r;
        for (int k0 = 0; k0 < 64; k0 += 32) {
            short8 af = *(const short8*)&QK[0][rowA * 64 + ((((k0 >> 3) + qd) ^ (rowA & 7)) << 3)];
            for (int j = 0; j < 8; j++) {
                const int rowB = j * 16 + r;
                short8 bf = *(const short8*)&QK[1][rowB * 64 + ((((k0 >> 3) + qd) ^ (rowB & 7)) << 3)];
                accS[im][j] = mfma16(af, bf, accS[im][j]);
            }
        }
    }
    __syncthreads();                                         // Vs reads done everywhere

    for (int im = 0; im < 2; im++) {
        const int i = w * 2 + im;
        for (int j = 0; j < 8; j++)
            for (int t4 = 0; t4 < 4; t4++) {
                const int row = i * 16 + qd * 4 + t4;
                const int col = j * 16 + r;
                Sc[row * 128 + (((col >> 2) ^ (row & 31)) << 2) + (col & 3)] =
                    accS[im][j][t4] * 0.125f;
            }
    }
    __syncthreads();

    // causal softmax: 2 threads per row (halves of 64 cols each)
    {
        const int s = tid & 127, half = tid >> 7;
        float mx = -1e30f;
        for (int g = half * 16; g < half * 16 + 16; g++) {
            if (4 * g > s) break;
            float4 v4 = *(const float4*)&Sc[s * 128 + ((g ^ (s & 31)) << 2)];
            mx = fmaxf(mx, v4.x);
            if (4 * g + 1 <= s) mx = fmaxf(mx, v4.y);
            if (4 * g + 2 <= s) mx = fmaxf(mx, v4.z);
            if (4 * g + 3 <= s) mx = fmaxf(mx, v4.w);
        }
        pmax[half][s] = mx;
    }
    __syncthreads();
    {
        const int s = tid & 127, half = tid >> 7;
        const float mx = fmaxf(pmax[0][s], pmax[1][s]);
        unsigned short* Pb = &QK[0][0];                      // [128]x16 slots, mask row&15
        float sum = 0.f;
        for (int gg = half * 8; gg < half * 8 + 8; gg++) {
            unsigned short o8[8] = {0, 0, 0, 0, 0, 0, 0, 0};
            const int c0 = gg * 8;
            if (c0 <= s) {
                float4 a4 = *(const float4*)&Sc[s * 128 + (((2 * gg) ^ (s & 31)) << 2)];
                float4 b4 = *(const float4*)&Sc[s * 128 + (((2 * gg + 1) ^ (s & 31)) << 2)];
                float e;
                e = __expf(a4.x - mx);                sum += e; o8[0] = f2b(e);
                if (c0 + 1 <= s) { e = __expf(a4.y - mx); sum += e; o8[1] = f2b(e); }
                if (c0 + 2 <= s) { e = __expf(a4.z - mx); sum += e; o8[2] = f2b(e); }
                if (c0 + 3 <= s) { e = __expf(a4.w - mx); sum += e; o8[3] = f2b(e); }
                if (c0 + 4 <= s) { e = __expf(b4.x - mx); sum += e; o8[4] = f2b(e); }
                if (c0 + 5 <= s) { e = __expf(b4.y - mx); sum += e; o8[5] = f2b(e); }
                if (c0 + 6 <= s) { e = __expf(b4.z - mx); sum += e; o8[6] = f2b(e); }
                if (c0 + 7 <= s) { e = __expf(b4.w - mx); sum += e; o8[7] = f2b(e); }
            }
            *(uint4*)&Pb[s * 128 + ((gg ^ (s & 15)) << 3)] = *(uint4*)o8;
        }
        psum[half][s] = sum;
    }
    __syncthreads();
    if (tid < 128) rsum[tid] = 1.f / (psum[0][tid] + psum[1][tid]);

    // Y = (P V) * rsum
    const unsigned short* Pb = &QK[0][0];
    float4v accO[2][4];
    { float4v z = {0,0,0,0}; for (int a = 0; a < 2; a++) for (int j = 0; j < 4; j++) accO[a][j] = z; }
    for (int im = 0; im < 2; im++) {
        const int i = w * 2 + im;
        const int rowA = i * 16 + r;
        for (int k0 = 0; k0 < 128; k0 += 32) {
            short8 af = *(const short8*)&Pb[rowA * 128 + ((((k0 >> 3) + qd) ^ (rowA & 15)) << 3)];
            for (int j = 0; j < 4; j++) {
                const int rowB = j * 16 + r;
                short8 bf = *(const short8*)&Vt[rowB * 128 + ((((k0 >> 3) + qd) ^ (rowB & 15)) << 3)];
                accO[im][j] = mfma16(af, bf, accO[im][j]);
            }
        }
    }
    __syncthreads();                                         // rsum visible; Sc dead

    float* Ys = Sc;                                          // [128]x16 slots f32, mask row&15
    for (int im = 0; im < 2; im++) {
        const int i = w * 2 + im;
        for (int j = 0; j < 4; j++)
            for (int t4 = 0; t4 < 4; t4++) {
                const int row = i * 16 + qd * 4 + t4;
                const int col = j * 16 + r;
                Ys[row * 64 + (((col >> 2) ^ (row & 15)) << 2) + (col & 3)] =
                    accO[im][j][t4] * rsum[row];
            }
    }
    __syncthreads();
    for (int idx = tid; idx < 1024; idx += 256) {
        const int row = idx >> 3, gg = idx & 7;
        float4 a4 = *(const float4*)&Ys[row * 64 + (((2 * gg) ^ (row & 15)) << 2)];
        float4 b4 = *(const float4*)&Ys[row * 64 + (((2 * gg + 1) ^ (row & 15)) << 2)];
        unsigned short o8[8];
        o8[0] = f2b(a4.x); o8[1] = f2b(a4.y); o8[2] = f2b(a4.z); o8[3] = f2b(a4.w);
        o8[4] = f2b(b4.x); o8[5] = f2b(b4.y); o8[6] = f2b(b4.z); o8[7] = f2b(b4.w);
        *(uint4*)&ym[base + (size_t)row * 1024 + gg * 8] = *(uint4*)o8;
    }
}

// ---------------------------------------------------------------------------
// Final: LN(x[bn,126,:]) @ head_W -> out. One block per bn. (R2, unchanged)
// ---------------------------------------------------------------------------
__global__ __launch_bounds__(256) void final_kernel(
    const float* __restrict__ x, const float* __restrict__ lnw,
    const float* __restrict__ lnb, const float* __restrict__ headW,
    float* __restrict__ out)
{
    const int bn = blockIdx.x;
    const int tid = threadIdx.x;
    const float* xr = x + ((size_t)bn * 128 + 126) * 1024;
    float4 v = *(const float4*)&xr[tid * 4];
    float s  = v.x + v.y + v.z + v.w;
    float s2 = v.x * v.x + v.y * v.y + v.z * v.z + v.w * v.w;
    for (int o = 32; o > 0; o >>= 1) { s += __shfl_down(s, o); s2 += __shfl_down(s2, o); }
    __shared__ float ls[4], ls2[4];
    if ((tid & 63) == 0) { ls[tid >> 6] = s; ls2[tid >> 6] = s2; }
    __syncthreads();
    s  = ls[0] + ls[1] + ls[2] + ls[3];
    s2 = ls2[0] + ls2[1] + ls2[2] + ls2[3];
    float mean = s * (1.f / 1024.f);
    float var  = s2 * (1.f / 1024.f) - mean * mean;
    float inv  = rsqrtf(var + 1e-5f);
    __shared__ float hf[1024];
    float4 wv = *(const float4*)&lnw[tid * 4];
    float4 bv = *(const float4*)&lnb[tid * 4];
    hf[tid * 4 + 0] = (v.x - mean) * inv * wv.x + bv.x;
    hf[tid * 4 + 1] = (v.y - mean) * inv * wv.y + bv.y;
    hf[tid * 4 + 2] = (v.z - mean) * inv * wv.z + bv.z;
    hf[tid * 4 + 3] = (v.w - mean) * inv * wv.w + bv.w;
    __syncthreads();
    const int a = tid & 31, part = tid >> 5;
    float sum = 0.f;
    for (int c = part * 128; c < (part + 1) * 128; c++)
        sum += hf[c] * headW[(size_t)c * 32 + a];
    __shared__ float red[256];
    red[tid] = sum;
    __syncthreads();
    if (part == 0) {
        float tot = 0.f;
        for (int p = 0; p < 8; p++) tot += red[p * 32 + a];
        out[(size_t)bn * 32 + a] = tot;
    }
}

// ---------------------------------------------------------------------------
extern "C" void kernel_launch(void* const* d_in, const int* in_sizes, int n_in,
                              void* d_out, int out_size, void* d_ws, size_t ws_size,
                              hipStream_t stream)
{
    const float* states    = (const float*)d_in[0];
    const float* actions   = (const float*)d_in[1];
    const int*   timesteps = (const int*)  d_in[2];
    const float* pos_emb   = (const float*)d_in[3];
    const float* gpe_tab   = (const float*)d_in[4];
    const float* seW  = (const float*)d_in[5];
    const float* seb  = (const float*)d_in[6];
    const float* aeW  = (const float*)d_in[7];
    const float* aeb  = (const float*)d_in[8];
    const float* ln1w = (const float*)d_in[9];
    const float* ln1b = (const float*)d_in[10];
    const float* Wq = (const float*)d_in[11];
    const float* bq = (const float*)d_in[12];
    const float* Wk = (const float*)d_in[13];
    const float* bk = (const float*)d_in[14];
    const float* Wv = (const float*)d_in[15];
    const float* bv = (const float*)d_in[16];
    const float* Wp = (const float*)d_in[17];
    const float* bp = (const float*)d_in[18];
    const float* ln2w = (const float*)d_in[19];
    const float* ln2b = (const float*)d_in[20];
    const float* W1 = (const float*)d_in[21];
    const float* b1 = (const float*)d_in[22];
    const float* W2 = (const float*)d_in[23];
    const float* b2 = (const float*)d_in[24];
    const float* lnfw  = (const float*)d_in[25];
    const float* lnfb  = (const float*)d_in[26];
    const float* headW = (const float*)d_in[27];

    char* ws = (char*)d_ws;
    const size_t MB = 1024 * 1024;
    float*          x   = (float*)ws;                               // 64 MB
    unsigned short* h   = (unsigned short*)(ws + 64 * MB);          // 32 MB
    unsigned short* qb  = (unsigned short*)(ws + 96 * MB);          // 32 MB
    unsigned short* kb  = (unsigned short*)(ws + 128 * MB);         // 32 MB
    unsigned short* vb  = (unsigned short*)(ws + 160 * MB);         // 32 MB
    unsigned short* yb  = (unsigned short*)(ws + 192 * MB);         // 32 MB
    unsigned short* ub  = (unsigned short*)(ws + 96 * MB);          // 128 MB (aliases q/k/v/y)
    unsigned short* wqT = (unsigned short*)(ws + 224 * MB);         // 2 MB
    unsigned short* wkT = (unsigned short*)(ws + 226 * MB);
    unsigned short* wvT = (unsigned short*)(ws + 228 * MB);
    unsigned short* wpT = (unsigned short*)(ws + 230 * MB);
    unsigned short* w1T = (unsigned short*)(ws + 232 * MB);         // 8 MB
    unsigned short* w2T = (unsigned short*)(ws + 240 * MB);         // 8 MB (total 248 MB)

    embed_kernel<<<dim3(8, 512), 256, 0, stream>>>(
        states, actions, timesteps, pos_emb, gpe_tab, seW, seb, aeW, aeb, x);

    const long G = 128L * 1024L;            // gathered row stride (token 126 of each bn)
    float* xg = x + 126 * 1024;

    for (int lyr = 0; lyr < 8; lyr++) {
        const bool last = (lyr == 7);
        const size_t oC  = (size_t)lyr * 1024 * 1024;
        const size_t oC4 = (size_t)lyr * 1024 * 4096;
        transpose_kernel<<<dim3(32, 16),  256, 0, stream>>>(Wq + oC,  wqT, 1024, 1024);
        transpose_kernel<<<dim3(32, 16),  256, 0, stream>>>(Wk + oC,  wkT, 1024, 1024);
        transpose_kernel<<<dim3(32, 16),  256, 0, stream>>>(Wv + oC,  wvT, 1024, 1024);
        transpose_kernel<<<dim3(32, 16),  256, 0, stream>>>(Wp + oC,  wpT, 1024, 1024);
        transpose_kernel<<<dim3(128, 16), 256, 0, stream>>>(W1 + oC4, w1T, 1024, 4096);
        transpose_kernel<<<dim3(32, 64),  256, 0, stream>>>(W2 + oC4, w2T, 4096, 1024);

        ln_kernel<<<8192, 256, 0, stream>>>(x, 1024L, ln1w + lyr * 1024, ln1b + lyr * 1024, h);
        gemm_kernel<0><<<dim3(8, 128), 256, 0, stream>>>(h, wqT, bq + lyr * 1024, nullptr, qb, 1024, 1024, 1024L, 1024L);
        gemm_kernel<0><<<dim3(8, 128), 256, 0, stream>>>(h, wkT, bk + lyr * 1024, nullptr, kb, 1024, 1024, 1024L, 1024L);
        gemm_kernel<0><<<dim3(8, 128), 256, 0, stream>>>(h, wvT, bv + lyr * 1024, nullptr, vb, 1024, 1024, 1024L, 1024L);
        attn_kernel<<<2048, 256, 0, stream>>>(qb, kb, vb, yb);

        if (!last) {
            gemm_kernel<2><<<dim3(8, 128), 256, 0, stream>>>(yb, wpT, bp + lyr * 1024, x, x, 1024, 1024, 1024L, 1024L);
            ln_kernel<<<8192, 256, 0, stream>>>(x, 1024L, ln2w + lyr * 1024, ln2b + lyr * 1024, h);
            gemm_kernel<1><<<dim3(32, 128), 256, 0, stream>>>(h, w1T, b1 + lyr * 4096, nullptr, ub, 4096, 1024, 1024L, 4096L);
            gemm_kernel<2><<<dim3(8, 128), 256, 0, stream>>>(ub, w2T, b2 + lyr * 1024, x, x, 1024, 4096, 4096L, 1024L);
        } else {
            // only token 126 of each bn feeds the head -> 128-row trimmed path
            gemm_kernel<2><<<dim3(8, 1), 256, 0, stream>>>(yb + 126 * 1024, wpT, bp + lyr * 1024, xg, xg, 1024, 1024, G, G);
            ln_kernel<<<64, 256, 0, stream>>>(xg, G, ln2w + lyr * 1024, ln2b + lyr * 1024, h);
            gemm_kernel<1><<<dim3(32, 1), 256, 0, stream>>>(h, w1T, b1 + lyr * 4096, nullptr, ub, 4096, 1024, 1024L, 4096L);
            gemm_kernel<2><<<dim3(8, 1), 256, 0, stream>>>(ub, w2T, b2 + lyr * 1024, xg, xg, 1024, 4096, 4096L, G);
        }
    }

    final_kernel<<<128, 256, 0, stream>>>(x, lnfw, lnfb, headW, (float*)d_out);
}